// Round 3
// baseline (3216.331 us; speedup 1.0000x reference)
//
#include <hip/hip_runtime.h>
#include <hip/hip_bf16.h>
#include <math.h>

#define LN_EPS 1e-5f

typedef float v2f __attribute__((ext_vector_type(2)));

// Packed fp32 FMA: d = a*b + c on both halves. MI355X's 157 TF fp32 peak is
// only reachable via v_pk_fma_f32 (scalar v_fma_f32 is 78.6 TF).
__device__ __forceinline__ v2f pkfma(v2f a, v2f b, v2f c) {
    v2f d;
    asm("v_pk_fma_f32 %0, %1, %2, %3" : "=v"(d) : "v"(a), "v"(b), "v"(c));
    return d;
}

__device__ __forceinline__ v2f bc(float s) { v2f r; r.x = s; r.y = s; return r; }

// LayerNorm over 2*D2 values held as v2f[D2], then *g+b, then ReLU (in place).
template<int D2>
__device__ __forceinline__ void ln_relu2(v2f (&v)[D2],
                                         const float* __restrict__ g,
                                         const float* __restrict__ b) {
    const float invD = 1.0f / (float)(2 * D2);
    float m = 0.f;
#pragma unroll
    for (int i = 0; i < D2; ++i) m += v[i].x + v[i].y;
    m *= invD;
    float var = 0.f;
#pragma unroll
    for (int i = 0; i < D2; ++i) {
        float dx = v[i].x - m, dy = v[i].y - m;
        var = fmaf(dx, dx, var);
        var = fmaf(dy, dy, var);
    }
    var *= invD;
    const float rs = rsqrtf(var + LN_EPS);
    const v2f* g2 = (const v2f*)g;
    const v2f* b2 = (const v2f*)b;
#pragma unroll
    for (int i = 0; i < D2; ++i) {
        v2f t = pkfma((v[i] - m) * rs, g2[i], b2[i]);
        v[i].x = fmaxf(t.x, 0.f);
        v[i].y = fmaxf(t.y, 0.f);
    }
}

// y[2*OUT2] = x[2*IN2] @ W[2*IN2, 2*OUT2], no bias. W row-major.
template<int IN2, int OUT2>
__device__ __forceinline__ void mv2(const v2f (&x)[IN2],
                                    const float* __restrict__ W,
                                    v2f (&y)[OUT2]) {
    const v2f* W2 = (const v2f*)W;
#pragma unroll
    for (int j = 0; j < OUT2; ++j) { v2f z; z.x = 0.f; z.y = 0.f; y[j] = z; }
#pragma unroll
    for (int k2 = 0; k2 < IN2; ++k2) {
        const v2f x0 = bc(x[k2].x), x1 = bc(x[k2].y);
#pragma unroll
        for (int j = 0; j < OUT2; ++j) {
            y[j] = pkfma(x0, W2[(2 * k2) * OUT2 + j], y[j]);
            y[j] = pkfma(x1, W2[(2 * k2 + 1) * OUT2 + j], y[j]);
        }
    }
}

// y[2*OUT2] = x[2*IN2] @ W + bias
template<int IN2, int OUT2>
__device__ __forceinline__ void mv2_bias(const v2f (&x)[IN2],
                                         const float* __restrict__ W,
                                         const float* __restrict__ bias,
                                         v2f (&y)[OUT2]) {
    const v2f* W2 = (const v2f*)W;
    const v2f* b2 = (const v2f*)bias;
#pragma unroll
    for (int j = 0; j < OUT2; ++j) y[j] = b2[j];
#pragma unroll
    for (int k2 = 0; k2 < IN2; ++k2) {
        const v2f x0 = bc(x[k2].x), x1 = bc(x[k2].y);
#pragma unroll
        for (int j = 0; j < OUT2; ++j) {
            y[j] = pkfma(x0, W2[(2 * k2) * OUT2 + j], y[j]);
            y[j] = pkfma(x1, W2[(2 * k2 + 1) * OUT2 + j], y[j]);
        }
    }
}

// 2 rows per thread: weight loads amortized across rows; launch_bounds(,2)
// gives the allocator ~256 VGPRs for 128 accumulator regs + deep prefetch.
__global__ __launch_bounds__(256, 2) void opening_critic_kernel(
    const float* __restrict__ rep,      // [N,128]
    const float* __restrict__ pose,     // [N,6]
    const float* __restrict__ opening,  // [N,1]
    const float* __restrict__ kw1, const float* __restrict__ kg,  const float* __restrict__ kb,
    const float* __restrict__ kw2, const float* __restrict__ kb2,
    const float* __restrict__ qw1, const float* __restrict__ qg,  const float* __restrict__ qb,
    const float* __restrict__ qw2, const float* __restrict__ qb2,
    const float* __restrict__ vw1, const float* __restrict__ vg,  const float* __restrict__ vb,
    const float* __restrict__ vw2, const float* __restrict__ vb2,
    const float* __restrict__ aw1, const float* __restrict__ ag,  const float* __restrict__ ab,
    const float* __restrict__ aw2, const float* __restrict__ ab2,
    const float* __restrict__ rw1, const float* __restrict__ rg1, const float* __restrict__ rb1,
    const float* __restrict__ rw2, const float* __restrict__ rg2, const float* __restrict__ rb2,
    const float* __restrict__ rw3, const float* __restrict__ rb3,
    const float* __restrict__ gw1, const float* __restrict__ gg,  const float* __restrict__ gb,
    const float* __restrict__ gw2, const float* __restrict__ gb2,
    float* __restrict__ out, int n)
{
    // Per-thread private slots; each thread only touches [.][.][tid] -> no
    // __syncthreads() needed, no barrier drain. 2-way bank aliasing is free.
    __shared__ v2f keybuf[2][16][256];

    const int tid = threadIdx.x;
    const int base = blockIdx.x * 512;
    const int r0 = base + tid;
    const int r1 = base + 256 + tid;
    const bool a0 = (r0 < n), a1 = (r1 < n);
    const int rr[2] = { a0 ? r0 : (n - 1), a1 ? r1 : (n - 1) };

    const float4* rep0 = (const float4*)(rep + (size_t)rr[0] * 128);
    const float4* rep1 = (const float4*)(rep + (size_t)rr[1] * 128);

    // ---------------- Pass A: ka = rep @ kw1 (128->64), 2 rows ----------------
    {
        v2f ka[2][32];
#pragma unroll
        for (int j = 0; j < 32; ++j) { ka[0][j] = bc(0.f); ka[1][j] = bc(0.f); }

#pragma unroll 2
        for (int k4 = 0; k4 < 32; ++k4) {
            const float4 x0 = rep0[k4];
            const float4 x1 = rep1[k4];
            const v2f* w = (const v2f*)(kw1 + (size_t)k4 * 256);
            const v2f b00 = bc(x0.x), b01 = bc(x0.y), b02 = bc(x0.z), b03 = bc(x0.w);
            const v2f b10 = bc(x1.x), b11 = bc(x1.y), b12 = bc(x1.z), b13 = bc(x1.w);
#pragma unroll
            for (int j = 0; j < 32; ++j) {
                const v2f w0 = w[j], w1 = w[32 + j], w2 = w[64 + j], w3 = w[96 + j];
                ka[0][j] = pkfma(b00, w0, ka[0][j]);
                ka[0][j] = pkfma(b01, w1, ka[0][j]);
                ka[0][j] = pkfma(b02, w2, ka[0][j]);
                ka[0][j] = pkfma(b03, w3, ka[0][j]);
                ka[1][j] = pkfma(b10, w0, ka[1][j]);
                ka[1][j] = pkfma(b11, w1, ka[1][j]);
                ka[1][j] = pkfma(b12, w2, ka[1][j]);
                ka[1][j] = pkfma(b13, w3, ka[1][j]);
            }
        }

#pragma unroll
        for (int z = 0; z < 2; ++z) {
            ln_relu2<32>(ka[z], kg, kb);
            v2f key[16];
            mv2_bias<32, 16>(ka[z], kw2, kb2, key);
#pragma unroll
            for (int j = 0; j < 16; ++j) keybuf[z][j][tid] = key[j];
        }
    }

    // small per-row inputs
    float pv[2][6];
    float ov[2];
#pragma unroll
    for (int z = 0; z < 2; ++z) {
#pragma unroll
        for (int i = 0; i < 6; ++i) pv[z][i] = pose[(size_t)rr[z] * 6 + i];
        ov[z] = opening[rr[z]];
    }

    // ---------------- Pass B: ra = [rep,pose,open] @ rw1 (135->64), 2 rows ----------------
    v2f ra[2][32];
    {
#pragma unroll
        for (int j = 0; j < 32; ++j) { ra[0][j] = bc(0.f); ra[1][j] = bc(0.f); }

#pragma unroll 2
        for (int k4 = 0; k4 < 32; ++k4) {
            const float4 x0 = rep0[k4];
            const float4 x1 = rep1[k4];
            const v2f* w = (const v2f*)(rw1 + (size_t)k4 * 256);
            const v2f b00 = bc(x0.x), b01 = bc(x0.y), b02 = bc(x0.z), b03 = bc(x0.w);
            const v2f b10 = bc(x1.x), b11 = bc(x1.y), b12 = bc(x1.z), b13 = bc(x1.w);
#pragma unroll
            for (int j = 0; j < 32; ++j) {
                const v2f w0 = w[j], w1 = w[32 + j], w2 = w[64 + j], w3 = w[96 + j];
                ra[0][j] = pkfma(b00, w0, ra[0][j]);
                ra[0][j] = pkfma(b01, w1, ra[0][j]);
                ra[0][j] = pkfma(b02, w2, ra[0][j]);
                ra[0][j] = pkfma(b03, w3, ra[0][j]);
                ra[1][j] = pkfma(b10, w0, ra[1][j]);
                ra[1][j] = pkfma(b11, w1, ra[1][j]);
                ra[1][j] = pkfma(b12, w2, ra[1][j]);
                ra[1][j] = pkfma(b13, w3, ra[1][j]);
            }
        }
        // pose rows 128..133, opening row 134
#pragma unroll
        for (int kk = 0; kk < 6; ++kk) {
            const v2f* w = (const v2f*)(rw1 + (128 + kk) * 64);
            const v2f x0 = bc(pv[0][kk]), x1 = bc(pv[1][kk]);
#pragma unroll
            for (int j = 0; j < 32; ++j) {
                ra[0][j] = pkfma(x0, w[j], ra[0][j]);
                ra[1][j] = pkfma(x1, w[j], ra[1][j]);
            }
        }
        {
            const v2f* w = (const v2f*)(rw1 + 134 * 64);
            const v2f x0 = bc(ov[0]), x1 = bc(ov[1]);
#pragma unroll
            for (int j = 0; j < 32; ++j) {
                ra[0][j] = pkfma(x0, w[j], ra[0][j]);
                ra[1][j] = pkfma(x1, w[j], ra[1][j]);
            }
        }
    }

    // ---------------- Tail per row ----------------
#pragma unroll
    for (int z = 0; z < 2; ++z) {
        // residual branch
        ln_relu2<32>(ra[z], rg1, rb1);
        v2f h2[16];
        mv2<32, 16>(ra[z], rw2, h2);
        ln_relu2<16>(h2, rg2, rb2);
        v2f residuals[8];
        mv2_bias<16, 8>(h2, rw3, rb3, residuals);

        // query branch: 6 -> 16 -> 32
        v2f query[16];
        {
            v2f q1[8];
            const v2f* qw1_2 = (const v2f*)qw1;
#pragma unroll
            for (int j = 0; j < 8; ++j) q1[j] = bc(0.f);
#pragma unroll
            for (int k = 0; k < 6; ++k) {
                const v2f xv = bc(pv[z][k]);
#pragma unroll
                for (int j = 0; j < 8; ++j) q1[j] = pkfma(xv, qw1_2[k * 8 + j], q1[j]);
            }
            ln_relu2<8>(q1, qg, qb);
            mv2_bias<8, 16>(q1, qw2, qb2, query);
        }

        // value branch: 1 -> 16 -> 32
        v2f value[16];
        {
            v2f v1[8];
            const v2f* vw1_2 = (const v2f*)vw1;
            const v2f xo = bc(ov[z]);
#pragma unroll
            for (int j = 0; j < 8; ++j) v1[j] = xo * vw1_2[j];
            ln_relu2<8>(v1, vg, vb);
            mv2_bias<8, 16>(v1, vw2, vb2, value);
        }

        // attention combine: softmax(q*k) * v
        v2f s[16];
#pragma unroll
        for (int j = 0; j < 16; ++j) s[j] = query[j] * keybuf[z][j][tid];
        float mx = -1e30f;
#pragma unroll
        for (int j = 0; j < 16; ++j) mx = fmaxf(mx, fmaxf(s[j].x, s[j].y));
        float sum = 0.f;
#pragma unroll
        for (int j = 0; j < 16; ++j) {
            s[j].x = __expf(s[j].x - mx);
            s[j].y = __expf(s[j].y - mx);
            sum += s[j].x + s[j].y;
        }
        const float inv = 1.0f / sum;
#pragma unroll
        for (int j = 0; j < 16; ++j) s[j] = s[j] * inv * value[j];

        // attention head: 32 -> 32 -> 16
        v2f att[8];
        {
            v2f a1[16];
            mv2<16, 16>(s, aw1, a1);
            ln_relu2<16>(a1, ag, ab);
            mv2_bias<16, 8>(a1, aw2, ab2, att);
        }

        // get_value on concat([att, residuals]) : 32 -> 16 -> 1
        float score;
        {
            v2f g1[8];
            const v2f* gw1_2 = (const v2f*)gw1;
#pragma unroll
            for (int j = 0; j < 8; ++j) g1[j] = bc(0.f);
#pragma unroll
            for (int k2 = 0; k2 < 8; ++k2) {
                const v2f x0 = bc(att[k2].x), x1 = bc(att[k2].y);
#pragma unroll
                for (int j = 0; j < 8; ++j) {
                    g1[j] = pkfma(x0, gw1_2[(2 * k2) * 8 + j], g1[j]);
                    g1[j] = pkfma(x1, gw1_2[(2 * k2 + 1) * 8 + j], g1[j]);
                }
            }
#pragma unroll
            for (int k2 = 0; k2 < 8; ++k2) {
                const v2f x0 = bc(residuals[k2].x), x1 = bc(residuals[k2].y);
#pragma unroll
                for (int j = 0; j < 8; ++j) {
                    g1[j] = pkfma(x0, gw1_2[(16 + 2 * k2) * 8 + j], g1[j]);
                    g1[j] = pkfma(x1, gw1_2[(16 + 2 * k2 + 1) * 8 + j], g1[j]);
                }
            }
            ln_relu2<8>(g1, gg, gb);
            score = gb2[0];
            const v2f* gw2_2 = (const v2f*)gw2;
#pragma unroll
            for (int k = 0; k < 8; ++k) {
                score = fmaf(g1[k].x, gw2_2[k].x, score);
                score = fmaf(g1[k].y, gw2_2[k].y, score);
            }
        }

        if (z == 0) { if (a0) out[r0] = score; }
        else        { if (a1) out[r1] = score; }
    }
}

extern "C" void kernel_launch(void* const* d_in, const int* in_sizes, int n_in,
                              void* d_out, int out_size, void* d_ws, size_t ws_size,
                              hipStream_t stream) {
    const float* rep     = (const float*)d_in[0];
    const float* pose    = (const float*)d_in[1];
    const float* opening = (const float*)d_in[2];
    const float* kw1 = (const float*)d_in[3];
    const float* kg  = (const float*)d_in[4];
    const float* kb  = (const float*)d_in[5];
    const float* kw2 = (const float*)d_in[6];
    const float* kb2 = (const float*)d_in[7];
    const float* qw1 = (const float*)d_in[8];
    const float* qg  = (const float*)d_in[9];
    const float* qb  = (const float*)d_in[10];
    const float* qw2 = (const float*)d_in[11];
    const float* qb2 = (const float*)d_in[12];
    const float* vw1 = (const float*)d_in[13];
    const float* vg  = (const float*)d_in[14];
    const float* vb  = (const float*)d_in[15];
    const float* vw2 = (const float*)d_in[16];
    const float* vb2 = (const float*)d_in[17];
    const float* aw1 = (const float*)d_in[18];
    const float* ag  = (const float*)d_in[19];
    const float* ab  = (const float*)d_in[20];
    const float* aw2 = (const float*)d_in[21];
    const float* ab2 = (const float*)d_in[22];
    const float* rw1 = (const float*)d_in[23];
    const float* rg1 = (const float*)d_in[24];
    const float* rb1 = (const float*)d_in[25];
    const float* rw2 = (const float*)d_in[26];
    const float* rg2 = (const float*)d_in[27];
    const float* rb2 = (const float*)d_in[28];
    const float* rw3 = (const float*)d_in[29];
    const float* rb3 = (const float*)d_in[30];
    const float* gw1 = (const float*)d_in[31];
    const float* gg  = (const float*)d_in[32];
    const float* gb  = (const float*)d_in[33];
    const float* gw2 = (const float*)d_in[34];
    const float* gb2 = (const float*)d_in[35];

    const int n = in_sizes[0] / 128;   // 524288 rows
    float* out = (float*)d_out;

    dim3 block(256);
    dim3 grid((n + 511) / 512);        // 2 rows per thread
    hipLaunchKernelGGL(opening_critic_kernel, grid, block, 0, stream,
                       rep, pose, opening,
                       kw1, kg, kb, kw2, kb2,
                       qw1, qg, qb, qw2, qb2,
                       vw1, vg, vb, vw2, vb2,
                       aw1, ag, ab, aw2, ab2,
                       rw1, rg1, rb1, rw2, rg2, rb2, rw3, rb3,
                       gw1, gg, gb, gw2, gb2,
                       out, n);
}

// Round 4
// 716.653 us; speedup vs baseline: 4.4880x; 4.4880x over previous
//
#include <hip/hip_runtime.h>
#include <math.h>

#define LN_EPS 1e-5f

typedef float v2f  __attribute__((ext_vector_type(2)));
typedef float f32x4 __attribute__((ext_vector_type(4)));
typedef short s16x8 __attribute__((ext_vector_type(8)));   // 8 bf16 in 4 VGPRs (guide §3)

__device__ __forceinline__ v2f pf(v2f a, v2f b, v2f c) {
    return __builtin_elementwise_fma(a, b, c);
}
__device__ __forceinline__ v2f bc2(float s) { v2f r; r.x = s; r.y = s; return r; }

// fp32 -> bf16 (RNE), bf16 -> fp32
__device__ __forceinline__ short f2bf(float f) {
    union { float f; unsigned u; } v; v.f = f;
    return (short)((v.u + 0x7fffu + ((v.u >> 16) & 1u)) >> 16);
}
__device__ __forceinline__ float bf2f(short s) {
    union { unsigned u; float f; } v; v.u = ((unsigned)(unsigned short)s) << 16;
    return v.f;
}

// LayerNorm over 2*D2 values held as v2f[D2], then *g+b, then ReLU (in place).
template<int D2>
__device__ __forceinline__ void ln_relu2(v2f (&v)[D2],
                                         const float* __restrict__ g,
                                         const float* __restrict__ b) {
    const float invD = 1.0f / (float)(2 * D2);
    float m = 0.f;
#pragma unroll
    for (int i = 0; i < D2; ++i) m += v[i].x + v[i].y;
    m *= invD;
    float var = 0.f;
#pragma unroll
    for (int i = 0; i < D2; ++i) {
        float dx = v[i].x - m, dy = v[i].y - m;
        var = fmaf(dx, dx, var);
        var = fmaf(dy, dy, var);
    }
    var *= invD;
    const float rs = rsqrtf(var + LN_EPS);
    const v2f* g2 = (const v2f*)g;
    const v2f* b2 = (const v2f*)b;
#pragma unroll
    for (int i = 0; i < D2; ++i) {
        v2f t = pf((v[i] - m) * rs, g2[i], b2[i]);
        v[i].x = fmaxf(t.x, 0.f);
        v[i].y = fmaxf(t.y, 0.f);
    }
}

template<int IN2, int OUT2>
__device__ __forceinline__ void mv2(const v2f (&x)[IN2],
                                    const float* __restrict__ W,
                                    v2f (&y)[OUT2]) {
    const v2f* W2 = (const v2f*)W;
#pragma unroll
    for (int j = 0; j < OUT2; ++j) y[j] = bc2(0.f);
#pragma unroll
    for (int k2 = 0; k2 < IN2; ++k2) {
        const v2f x0 = bc2(x[k2].x), x1 = bc2(x[k2].y);
#pragma unroll
        for (int j = 0; j < OUT2; ++j) {
            y[j] = pf(x0, W2[(2 * k2) * OUT2 + j], y[j]);
            y[j] = pf(x1, W2[(2 * k2 + 1) * OUT2 + j], y[j]);
        }
    }
}

template<int IN2, int OUT2>
__device__ __forceinline__ void mv2_bias(const v2f (&x)[IN2],
                                         const float* __restrict__ W,
                                         const float* __restrict__ bias,
                                         v2f (&y)[OUT2]) {
    const v2f* W2 = (const v2f*)W;
    const v2f* b2 = (const v2f*)bias;
#pragma unroll
    for (int j = 0; j < OUT2; ++j) y[j] = b2[j];
#pragma unroll
    for (int k2 = 0; k2 < IN2; ++k2) {
        const v2f x0 = bc2(x[k2].x), x1 = bc2(x[k2].y);
#pragma unroll
        for (int j = 0; j < OUT2; ++j) {
            y[j] = pf(x0, W2[(2 * k2) * OUT2 + j], y[j]);
            y[j] = pf(x1, W2[(2 * k2 + 1) * OUT2 + j], y[j]);
        }
    }
}

// One MFMA phase: row[0..63] (this lane's row of  X[128-wide slice] @ W[128,64])
// W row-major [128][64]. Result is PRE-LayerNorm, fp32 (via bf16 LDS round-trip).
// MFMA layouts (guide §3, HW-verified m89/m91/m120):
//   A[m=lane&15][k=quad*8+j]  B[k=quad*8+j][n=lane&15]  D: col=lane&15,row=quad*4+reg
__device__ __forceinline__ void mfma_phase(const float* __restrict__ rep,
                                           const float* __restrict__ W,
                                           int waveRow0, int lane, int nmax,
                                           short (*__restrict__ scratch)[72],
                                           v2f (&row)[32]) {
    const int lm = lane & 15, quad = lane >> 4;

    // B-fragments: loop-invariant, 16 frags x 4 VGPRs = 64 VGPRs
    s16x8 bfr[4][4];
#pragma unroll
    for (int kc = 0; kc < 4; ++kc) {
#pragma unroll
        for (int ct = 0; ct < 4; ++ct) {
            const float* wp = W + (size_t)(kc * 32 + quad * 8) * 64 + ct * 16 + lm;
            s16x8 t;
#pragma unroll
            for (int j = 0; j < 8; ++j) t[j] = f2bf(wp[j * 64]);
            bfr[kc][ct] = t;
        }
    }

#pragma unroll
    for (int rt = 0; rt < 4; ++rt) {
        int arow = waveRow0 + rt * 16 + lm;
        if (arow >= nmax) arow = nmax - 1;
        const float* ap = rep + (size_t)arow * 128 + quad * 8;

        s16x8 afr[4];
#pragma unroll
        for (int kc = 0; kc < 4; ++kc) {
            const float4 x0 = *(const float4*)(ap + kc * 32);
            const float4 x1 = *(const float4*)(ap + kc * 32 + 4);
            s16x8 t;
            t[0] = f2bf(x0.x); t[1] = f2bf(x0.y); t[2] = f2bf(x0.z); t[3] = f2bf(x0.w);
            t[4] = f2bf(x1.x); t[5] = f2bf(x1.y); t[6] = f2bf(x1.z); t[7] = f2bf(x1.w);
            afr[kc] = t;
        }

        f32x4 acc[4];
#pragma unroll
        for (int ct = 0; ct < 4; ++ct) acc[ct] = (f32x4){0.f, 0.f, 0.f, 0.f};
#pragma unroll
        for (int kc = 0; kc < 4; ++kc) {
#pragma unroll
            for (int ct = 0; ct < 4; ++ct)
                acc[ct] = __builtin_amdgcn_mfma_f32_16x16x32_bf16(
                    afr[kc], bfr[kc][ct], acc[ct], 0, 0, 0);
        }

        // scatter D (C-layout) to wave-private scratch, bf16
#pragma unroll
        for (int ct = 0; ct < 4; ++ct) {
#pragma unroll
            for (int reg = 0; reg < 4; ++reg)
                scratch[rt * 16 + quad * 4 + reg][ct * 16 + lm] = f2bf(acc[ct][reg]);
        }
    }

    // intra-wave exchange: all scatter writes drained, then gather own row.
    asm volatile("s_waitcnt lgkmcnt(0)" ::: "memory");
    const short* sr = scratch[lane];
#pragma unroll
    for (int c = 0; c < 32; ++c) {
        v2f t; t.x = bf2f(sr[2 * c]); t.y = bf2f(sr[2 * c + 1]);
        row[c] = t;
    }
    asm volatile("s_waitcnt lgkmcnt(0)" ::: "memory");  // reads done before scratch reuse
}

__global__ __launch_bounds__(256) void opening_critic_kernel(
    const float* __restrict__ rep, const float* __restrict__ pose,
    const float* __restrict__ opening,
    const float* __restrict__ kw1, const float* __restrict__ kg,  const float* __restrict__ kb,
    const float* __restrict__ kw2, const float* __restrict__ kb2,
    const float* __restrict__ qw1, const float* __restrict__ qg,  const float* __restrict__ qb,
    const float* __restrict__ qw2, const float* __restrict__ qb2,
    const float* __restrict__ vw1, const float* __restrict__ vg,  const float* __restrict__ vb,
    const float* __restrict__ vw2, const float* __restrict__ vb2,
    const float* __restrict__ aw1, const float* __restrict__ ag,  const float* __restrict__ ab,
    const float* __restrict__ aw2, const float* __restrict__ ab2,
    const float* __restrict__ rw1, const float* __restrict__ rg1, const float* __restrict__ rb1,
    const float* __restrict__ rw2, const float* __restrict__ rg2, const float* __restrict__ rb2,
    const float* __restrict__ rw3, const float* __restrict__ rb3,
    const float* __restrict__ gw1, const float* __restrict__ gg,  const float* __restrict__ gb,
    const float* __restrict__ gw2, const float* __restrict__ gb2,
    float* __restrict__ out, int n)
{
    __shared__ short scratch[4][64][72];   // 36.9 KB, per-wave C->row transpose buffer
    __shared__ v2f keybuf[16][256];        // 32 KB, per-thread key parking (no barrier)

    const int tid  = threadIdx.x;
    const int wave = tid >> 6, lane = tid & 63;
    const int blockRow0 = blockIdx.x * 256;
    const int waveRow0  = blockRow0 + wave * 64;
    const int myrow     = blockRow0 + tid;            // == waveRow0 + lane
    const bool active   = (myrow < n);
    const int rowc      = active ? myrow : (n - 1);

    // ---------------- Phase A: ka = rep @ kw1 (MFMA) ----------------
    {
        v2f ka[32];
        mfma_phase(rep, kw1, waveRow0, lane, n, scratch[wave], ka);
        ln_relu2<32>(ka, kg, kb);
        v2f key[16];
        mv2_bias<32, 16>(ka, kw2, kb2, key);
#pragma unroll
        for (int j = 0; j < 16; ++j) keybuf[j][tid] = key[j];
    }

    // per-row small inputs
    float pv[6];
#pragma unroll
    for (int i = 0; i < 6; ++i) pv[i] = pose[(size_t)rowc * 6 + i];
    const float ov = opening[rowc];

    // ---------------- Phase B: ra = rep @ rw1[0:128] (MFMA) + pose/open ----------------
    v2f ra[32];
    mfma_phase(rep, rw1, waveRow0, lane, n, scratch[wave], ra);
#pragma unroll
    for (int kk = 0; kk < 6; ++kk) {
        const v2f* w = (const v2f*)(rw1 + (128 + kk) * 64);
        const v2f xv = bc2(pv[kk]);
#pragma unroll
        for (int j = 0; j < 32; ++j) ra[j] = pf(xv, w[j], ra[j]);
    }
    {
        const v2f* w = (const v2f*)(rw1 + 134 * 64);
        const v2f xo = bc2(ov);
#pragma unroll
        for (int j = 0; j < 32; ++j) ra[j] = pf(xo, w[j], ra[j]);
    }

    // ---------------- per-thread tail (round-2 proven code) ----------------
    ln_relu2<32>(ra, rg1, rb1);
    v2f h2[16];
    mv2<32, 16>(ra, rw2, h2);
    ln_relu2<16>(h2, rg2, rb2);
    v2f residuals[8];
    mv2_bias<16, 8>(h2, rw3, rb3, residuals);

    // query: 6 -> 16 -> 32
    v2f query[16];
    {
        v2f q1[8];
        const v2f* qw1_2 = (const v2f*)qw1;
#pragma unroll
        for (int j = 0; j < 8; ++j) q1[j] = bc2(0.f);
#pragma unroll
        for (int k = 0; k < 6; ++k) {
            const v2f xv = bc2(pv[k]);
#pragma unroll
            for (int j = 0; j < 8; ++j) q1[j] = pf(xv, qw1_2[k * 8 + j], q1[j]);
        }
        ln_relu2<8>(q1, qg, qb);
        mv2_bias<8, 16>(q1, qw2, qb2, query);
    }

    // value: 1 -> 16 -> 32
    v2f value[16];
    {
        v2f v1[8];
        const v2f* vw1_2 = (const v2f*)vw1;
        const v2f xo = bc2(ov);
#pragma unroll
        for (int j = 0; j < 8; ++j) v1[j] = xo * vw1_2[j];
        ln_relu2<8>(v1, vg, vb);
        mv2_bias<8, 16>(v1, vw2, vb2, value);
    }

    // softmax(query*key) * value
    v2f s[16];
#pragma unroll
    for (int j = 0; j < 16; ++j) s[j] = query[j] * keybuf[j][tid];
    float mx = -1e30f;
#pragma unroll
    for (int j = 0; j < 16; ++j) mx = fmaxf(mx, fmaxf(s[j].x, s[j].y));
    float sum = 0.f;
#pragma unroll
    for (int j = 0; j < 16; ++j) {
        s[j].x = __expf(s[j].x - mx);
        s[j].y = __expf(s[j].y - mx);
        sum += s[j].x + s[j].y;
    }
    const float inv = 1.0f / sum;
#pragma unroll
    for (int j = 0; j < 16; ++j) s[j] = s[j] * inv * value[j];

    // attention head: 32 -> 32 -> 16
    v2f att[8];
    {
        v2f a1[16];
        mv2<16, 16>(s, aw1, a1);
        ln_relu2<16>(a1, ag, ab);
        mv2_bias<16, 8>(a1, aw2, ab2, att);
    }

    // get_value on concat([att, residuals]): 32 -> 16 -> 1
    float score;
    {
        v2f g1[8];
        const v2f* gw1_2 = (const v2f*)gw1;
#pragma unroll
        for (int j = 0; j < 8; ++j) g1[j] = bc2(0.f);
#pragma unroll
        for (int k2 = 0; k2 < 8; ++k2) {
            const v2f x0 = bc2(att[k2].x), x1 = bc2(att[k2].y);
#pragma unroll
            for (int j = 0; j < 8; ++j) {
                g1[j] = pf(x0, gw1_2[(2 * k2) * 8 + j], g1[j]);
                g1[j] = pf(x1, gw1_2[(2 * k2 + 1) * 8 + j], g1[j]);
            }
        }
#pragma unroll
        for (int k2 = 0; k2 < 8; ++k2) {
            const v2f x0 = bc2(residuals[k2].x), x1 = bc2(residuals[k2].y);
#pragma unroll
            for (int j = 0; j < 8; ++j) {
                g1[j] = pf(x0, gw1_2[(16 + 2 * k2) * 8 + j], g1[j]);
                g1[j] = pf(x1, gw1_2[(16 + 2 * k2 + 1) * 8 + j], g1[j]);
            }
        }
        ln_relu2<8>(g1, gg, gb);
        score = gb2[0];
        const v2f* gw2_2 = (const v2f*)gw2;
#pragma unroll
        for (int k = 0; k < 8; ++k) {
            score = fmaf(g1[k].x, gw2_2[k].x, score);
            score = fmaf(g1[k].y, gw2_2[k].y, score);
        }
    }

    if (active) out[myrow] = score;
}

extern "C" void kernel_launch(void* const* d_in, const int* in_sizes, int n_in,
                              void* d_out, int out_size, void* d_ws, size_t ws_size,
                              hipStream_t stream) {
    const float* rep     = (const float*)d_in[0];
    const float* pose    = (const float*)d_in[1];
    const float* opening = (const float*)d_in[2];
    const float* kw1 = (const float*)d_in[3];
    const float* kg  = (const float*)d_in[4];
    const float* kb  = (const float*)d_in[5];
    const float* kw2 = (const float*)d_in[6];
    const float* kb2 = (const float*)d_in[7];
    const float* qw1 = (const float*)d_in[8];
    const float* qg  = (const float*)d_in[9];
    const float* qb  = (const float*)d_in[10];
    const float* qw2 = (const float*)d_in[11];
    const float* qb2 = (const float*)d_in[12];
    const float* vw1 = (const float*)d_in[13];
    const float* vg  = (const float*)d_in[14];
    const float* vb  = (const float*)d_in[15];
    const float* vw2 = (const float*)d_in[16];
    const float* vb2 = (const float*)d_in[17];
    const float* aw1 = (const float*)d_in[18];
    const float* ag  = (const float*)d_in[19];
    const float* ab  = (const float*)d_in[20];
    const float* aw2 = (const float*)d_in[21];
    const float* ab2 = (const float*)d_in[22];
    const float* rw1 = (const float*)d_in[23];
    const float* rg1 = (const float*)d_in[24];
    const float* rb1 = (const float*)d_in[25];
    const float* rw2 = (const float*)d_in[26];
    const float* rg2 = (const float*)d_in[27];
    const float* rb2 = (const float*)d_in[28];
    const float* rw3 = (const float*)d_in[29];
    const float* rb3 = (const float*)d_in[30];
    const float* gw1 = (const float*)d_in[31];
    const float* gg  = (const float*)d_in[32];
    const float* gb  = (const float*)d_in[33];
    const float* gw2 = (const float*)d_in[34];
    const float* gb2 = (const float*)d_in[35];

    const int n = in_sizes[0] / 128;   // 524288 rows
    float* out = (float*)d_out;

    dim3 block(256);
    dim3 grid((n + 255) / 256);
    hipLaunchKernelGGL(opening_critic_kernel, grid, block, 0, stream,
                       rep, pose, opening,
                       kw1, kg, kb, kw2, kb2,
                       qw1, qg, qb, qw2, qb2,
                       vw1, vg, vb, vw2, vb2,
                       aw1, ag, ab, aw2, ab2,
                       rw1, rg1, rb1, rw2, rg2, rb2, rw3, rb3,
                       gw1, gg, gb, gw2, gb2,
                       out, n);
}